// Round 4
// baseline (88.344 us; speedup 1.0000x reference)
//
#include <hip/hip_runtime.h>
#include <stdint.h>

#define B_ 32
#define F_ 8
#define H_ 224
#define W_ 224
#define NPIX (H_ * W_)          // 50176
#define NFRAMES (B_ * F_)       // 256
#define CHSTRIDE (F_ * H_ * W_) // 401408
#define NT 1024
#define NW 16

#define GRAY_BYTES ((size_t)NFRAMES * NPIX)   // 12,845,056 (8-aligned)

// ---------------- Kernel 1: gray quantization ----------------
__device__ __forceinline__ uint8_t quant1(float s) {
    float gr = s / 3.0f;
    float v = floorf(gr * 255.0f);
    v = fminf(fmaxf(v, 0.0f), 255.0f);
    return (uint8_t)(int)v;
}

__global__ __launch_bounds__(256) void k_gray(const float* __restrict__ x,
                                              uchar4* __restrict__ g4, int nq4) {
    int t = blockIdx.x * blockDim.x + threadIdx.x;
    if (t >= nq4) return;
    int q = t * 4;
    int b = q / CHSTRIDE;
    int rem = q - b * CHSTRIDE;
    const float4* p0 = reinterpret_cast<const float4*>(x + (size_t)(b * 3 + 0) * CHSTRIDE + rem);
    const float4* p1 = reinterpret_cast<const float4*>(x + (size_t)(b * 3 + 1) * CHSTRIDE + rem);
    const float4* p2 = reinterpret_cast<const float4*>(x + (size_t)(b * 3 + 2) * CHSTRIDE + rem);
    float4 a = *p0, bb = *p1, c = *p2;
    uchar4 o;
    o.x = quant1(a.x + bb.x + c.x);
    o.y = quant1(a.y + bb.y + c.y);
    o.z = quant1(a.z + bb.z + c.z);
    o.w = quant1(a.w + bb.w + c.w);
    g4[t] = o;
}

// ---------------- helpers ----------------
__device__ __forceinline__ uint32_t udot4acc(uint32_t a, uint32_t b, uint32_t c) {
#if __has_builtin(__builtin_amdgcn_udot4)
    return __builtin_amdgcn_udot4(a, b, c, false);
#else
    c += (a & 0xffu) * (b & 0xffu);
    c += ((a >> 8) & 0xffu) * ((b >> 8) & 0xffu);
    c += ((a >> 16) & 0xffu) * ((b >> 16) & 0xffu);
    c += (a >> 24) * (b >> 24);
    return c;
#endif
}

// ---------------- pair pass: u8-packed histogram atomics ----------------
// Wave handles row r; lanes 0..55 each cover 4 consecutive columns via one
// dword load per row. Shifted-column B operand built with shfl + funnel shift.
// hist: u8 H[256][256] packed 4/word (word idx>>2, byte idx&3).
template<int DR, int DC>
__device__ __forceinline__ void pair_pass(const uint8_t* __restrict__ gf,
                                          uint32_t* hist, int wave, int lane) {
    constexpr int nr = H_ - DR;
    if (lane < 56) {
        for (int r = wave; r < nr; r += NW) {
            const uint32_t* rowA = reinterpret_cast<const uint32_t*>(gf + r * W_);
            uint32_t A = rowA[lane];
            uint32_t B;
            if (DR) {
                const uint32_t* rowB = reinterpret_cast<const uint32_t*>(gf + (r + DR) * W_);
                B = rowB[lane];
            } else {
                B = A;
            }
            uint32_t Bv;
            if (DC == 1) {
                uint32_t Bn = __shfl_down(B, 1, 64);
                Bv = (B >> 8) | (Bn << 24);          // bytes = cols 4l+1 .. 4l+4
            } else if (DC == -1) {
                uint32_t Bp = __shfl_up(B, 1, 64);
                Bv = (B << 8) | (Bp >> 24);          // bytes = cols 4l-1 .. 4l+2
            } else {
                Bv = B;
            }
            int cb = lane * 4;
            #pragma unroll
            for (int k = 0; k < 4; ++k) {
                bool valid = (DC == 1) ? (cb + k < W_ - 1)
                           : (DC == -1) ? (cb + k >= 1)
                           : true;
                if (valid) {
                    uint32_t a = (A  >> (8 * k)) & 0xffu;
                    uint32_t b = (Bv >> (8 * k)) & 0xffu;
                    uint32_t idx = (a << 8) | b;      // h[a][b], reference order
                    atomicAdd(&hist[idx >> 2], 1u << ((idx & 3) << 3));
                }
            }
        }
    }
}

// ---------------- Kernel 2: one (frame, offset) per block ----------------
// LDS: 64 KB u8 histogram + reduce scratch -> 2 blocks/CU, 8 waves/SIMD.
__global__ __launch_bounds__(NT, 8) void k_glcm(const uint8_t* __restrict__ g,
                                                double* __restrict__ s12,
                                                double* __restrict__ part) {
    __shared__ uint32_t hist[16384];   // u8 H[256][256], 4 counts/word
    __shared__ double red[NW * 8];

    const int bid = blockIdx.x;
    const int frame = bid >> 2;
    const int ofs = bid & 3;
    const uint8_t* __restrict__ gf = g + (size_t)frame * NPIX;
    const int tid = threadIdx.x, lane = tid & 63, wave = tid >> 6;

    // zero histogram (16384 words = 4096 uint4)
    uint4* h4 = reinterpret_cast<uint4*>(hist);
    #pragma unroll
    for (int i = 0; i < 4; ++i) h4[tid + (i << 10)] = make_uint4(0u, 0u, 0u, 0u);

    // std partials: only the offset-0 block of each frame
    uint32_t s1 = 0, s2 = 0;
    if (ofs == 0) {
        const uint32_t* g32 = reinterpret_cast<const uint32_t*>(gf);
        for (int i = tid; i < NPIX / 4; i += NT) {
            uint32_t w = g32[i];
            #pragma unroll
            for (int k = 0; k < 4; ++k) {
                uint32_t v = (w >> (8 * k)) & 0xffu;
                s1 += v;
                s2 += v * v;
            }
        }
    }
    __syncthreads();

    if (ofs == 0)      pair_pass<0,  1>(gf, hist, wave, lane);
    else if (ofs == 1) pair_pass<1,  1>(gf, hist, wave, lane);
    else if (ofs == 2) pair_pass<1,  0>(gf, hist, wave, lane);
    else               pair_pass<1, -1>(gf, hist, wave, lane);
    __syncthreads();

    // ---- linear stats + sum(h^2): one pass over all 16384 words ----
    // con = sum h[i][j] (i-j)^2 ; dis = sum h |i-j| ; hom = sum h/(1+(i-j)^2)
    // (W symmetric => transpose contributes equally; normalize by np, not 2np)
    uint32_t conU = 0, disU = 0, slinU = 0;
    float homF = 0.0f;
    #pragma unroll 4
    for (int itr = 0; itr < 16; ++itr) {
        int m = tid + (itr << 10);         // wave covers one full row i = wave+16*itr
        uint32_t w = hist[m];
        if (w) {                            // empty rows skip wave-uniformly (execz)
            int i = m >> 6;
            int j0 = (m & 63) << 2;
            int d0 = i - j0;
            slinU = udot4acc(w, w, slinU);
            #pragma unroll
            for (int k = 0; k < 4; ++k) {
                uint32_t b = (w >> (k << 3)) & 0xffu;
                int d = d0 - k;
                uint32_t d2 = (uint32_t)(d * d);
                conU += b * d2;
                disU += b * (uint32_t)(d < 0 ? -d : d);
                homF += (float)b * __builtin_amdgcn_rcpf(1.0f + (float)d2);
            }
        }
    }

    // ---- cross term sum h[i][j]*h[j][i] over 4x4 byte tiles ----
    // unit (it=lane, jt=(lane+s)&63), s = wave+16q: bijective over 64x64 tiles.
    // A reads bank (lane+s)&31, B reads bank lane&31 -> free 2-way alias.
    uint32_t scrU = 0;
    #pragma unroll
    for (int q = 0; q < 4; ++q) {
        int s = wave + (q << 4);
        int jt = (lane + s) & 63;
        int ab = (lane << 8) + jt;          // word of row 4*lane+k at +64*k
        int bb = (jt << 8) + lane;
        uint32_t A0 = hist[ab], A1 = hist[ab + 64], A2 = hist[ab + 128], A3 = hist[ab + 192];
        uint32_t B0 = hist[bb], B1 = hist[bb + 64], B2 = hist[bb + 128], B3 = hist[bb + 192];
        if ((A0 | A1 | A2 | A3) && (B0 | B1 | B2 | B3)) {
            // 4x4 byte transpose of B0..B3 via v_perm_b32
            uint32_t x0 = __builtin_amdgcn_perm(B1, B0, 0x05010400u); // B0[0],B1[0],B0[1],B1[1]
            uint32_t x1 = __builtin_amdgcn_perm(B1, B0, 0x07030602u); // B0[2],B1[2],B0[3],B1[3]
            uint32_t x2 = __builtin_amdgcn_perm(B3, B2, 0x05010400u);
            uint32_t x3 = __builtin_amdgcn_perm(B3, B2, 0x07030602u);
            uint32_t t0 = __builtin_amdgcn_perm(x2, x0, 0x05040100u); // col 0
            uint32_t t1 = __builtin_amdgcn_perm(x2, x0, 0x07060302u); // col 1
            uint32_t t2 = __builtin_amdgcn_perm(x3, x1, 0x05040100u); // col 2
            uint32_t t3 = __builtin_amdgcn_perm(x3, x1, 0x07060302u); // col 3
            scrU = udot4acc(A0, t0, scrU);
            scrU = udot4acc(A1, t1, scrU);
            scrU = udot4acc(A2, t2, scrU);
            scrU = udot4acc(A3, t3, scrU);
        }
    }

    // ---- fused block reduction of 6 doubles ----
    double vals[6] = {(double)s1, (double)s2, (double)conU,
                      (double)disU, (double)homF, (double)slinU + (double)scrU};
    #pragma unroll
    for (int off = 32; off; off >>= 1) {
        #pragma unroll
        for (int i = 0; i < 6; ++i) vals[i] += __shfl_down(vals[i], off, 64);
    }
    if (lane == 0) {
        #pragma unroll
        for (int i = 0; i < 6; ++i) red[wave * 8 + i] = vals[i];
    }
    __syncthreads();
    if (tid == 0) {
        double acc[6];
        #pragma unroll
        for (int i = 0; i < 6; ++i) {
            double t = red[i];
            for (int w = 1; w < NW; ++w) t += red[w * 8 + i];
            acc[i] = t;
        }
        double np = (ofs & 1) ? 49729.0 : 49952.0;
        double inv = 1.0 / np;
        part[bid * 4 + 0] = acc[2] * inv;                 // con_o
        part[bid * 4 + 1] = acc[3] * inv;                 // dis_o
        part[bid * 4 + 2] = acc[4] * inv;                 // hom_o
        part[bid * 4 + 3] = acc[5] / (2.0 * np * np);     // asm_o = (Slin+Scross)/(2 np^2)
        if (ofs == 0) {
            s12[frame * 2 + 0] = acc[0];
            s12[frame * 2 + 1] = acc[1];
        }
    }
}

// ---------------- Kernel 3: combine offsets, finalize ----------------
__global__ __launch_bounds__(256) void k_final(const double* __restrict__ s12,
                                               const double* __restrict__ part,
                                               float* __restrict__ out) {
    int f = threadIdx.x;                  // 256 frames, 1 block
    const double* p = part + (size_t)f * 16;
    double con = (p[0] + p[4] + p[8]  + p[12]) * 0.25;
    double dis = (p[1] + p[5] + p[9]  + p[13]) * 0.25;
    double hom = (p[2] + p[6] + p[10] + p[14]) * 0.25;
    double as  = (p[3] + p[7] + p[11] + p[15]) * 0.25;
    double N = (double)NPIX;
    double mean = s12[f * 2] / N;
    double var = s12[f * 2 + 1] / N - mean * mean;
    if (var < 0.0) var = 0.0;
    float* op = out + f * 6;
    op[0] = (float)sqrt(var);
    op[1] = (float)con;
    op[2] = (float)dis;
    op[3] = (float)hom;
    op[4] = (float)as;
    op[5] = (float)sqrt(as);
}

extern "C" void kernel_launch(void* const* d_in, const int* in_sizes, int n_in,
                              void* d_out, int out_size, void* d_ws, size_t ws_size,
                              hipStream_t stream) {
    const float* x = (const float*)d_in[0];
    float* out = (float*)d_out;
    uint8_t* g = (uint8_t*)d_ws;
    double* s12  = (double*)((uint8_t*)d_ws + GRAY_BYTES);                  // 256*2 doubles
    double* part = (double*)((uint8_t*)d_ws + GRAY_BYTES + NFRAMES * 16);   // 256*4*4 doubles

    const int npix_total = B_ * F_ * H_ * W_;   // 12,845,056
    const int nq4 = npix_total / 4;             // 3,211,264
    const int blocks1 = (nq4 + 255) / 256;      // 12,544

    k_gray<<<blocks1, 256, 0, stream>>>(x, (uchar4*)g, nq4);
    k_glcm<<<NFRAMES * 4, NT, 0, stream>>>(g, s12, part);
    k_final<<<1, 256, 0, stream>>>(s12, part, out);
}

// Round 5
// 80.903 us; speedup vs baseline: 1.0920x; 1.0920x over previous
//
#include <hip/hip_runtime.h>
#include <stdint.h>

#define B_ 32
#define F_ 8
#define H_ 224
#define W_ 224
#define NPIX (H_ * W_)          // 50176
#define NFRAMES (B_ * F_)       // 256
#define NT 1024
#define NW 16
#define NQ4 (NPIX / 4)          // 12544 dwords per frame

__device__ __forceinline__ uint32_t udot4acc(uint32_t a, uint32_t b, uint32_t c) {
#if __has_builtin(__builtin_amdgcn_udot4)
    return __builtin_amdgcn_udot4(a, b, c, false);
#else
    c += (a & 0xffu) * (b & 0xffu);
    c += ((a >> 8) & 0xffu) * ((b >> 8) & 0xffu);
    c += ((a >> 16) & 0xffu) * ((b >> 16) & 0xffu);
    c += (a >> 24) * (b >> 24);
    return c;
#endif
}

__device__ __forceinline__ uint32_t quant1(float s) {
    float gr = s / 3.0f;
    float v = floorf(gr * 255.0f);
    v = fminf(fmaxf(v, 0.0f), 255.0f);
    return (uint32_t)(int)v;
}

// ---- pair pass: LDS gray -> swizzled u8 histogram atomics ----
// Wave handles row r; lanes 0..55 read one dword (4 px) of row r and r+DR.
// Swizzle: word = ((a<<6)|(b>>2)) ^ ((a&7)<<3)  -> spreads concentrated b
// across bank bits [5:3] via near-uniform a&7 (data ~N(127,42^2)).
template<int DR, int DC>
__device__ __forceinline__ void pair_pass(const uint32_t* __restrict__ gsh,
                                          uint32_t* hist, int wave, int lane) {
    constexpr int nr = H_ - DR;
    if (lane < 56) {
        for (int r = wave; r < nr; r += NW) {
            uint32_t A = gsh[r * 56 + lane];
            uint32_t B = DR ? gsh[(r + DR) * 56 + lane] : A;
            uint32_t Bv;
            if (DC == 1) {
                uint32_t Bn = __shfl_down(B, 1, 64);
                Bv = (B >> 8) | (Bn << 24);          // bytes = cols 4l+1 .. 4l+4
            } else if (DC == -1) {
                uint32_t Bp = __shfl_up(B, 1, 64);
                Bv = (B << 8) | (Bp >> 24);          // bytes = cols 4l-1 .. 4l+2
            } else {
                Bv = B;
            }
            int cb = lane * 4;
            #pragma unroll
            for (int k = 0; k < 4; ++k) {
                bool valid = (DC == 1) ? (cb + k < W_ - 1)
                           : (DC == -1) ? (cb + k >= 1)
                           : true;
                if (valid) {
                    uint32_t a = (A  >> (8 * k)) & 0xffu;
                    uint32_t b = (Bv >> (8 * k)) & 0xffu;
                    uint32_t w = ((a << 6) | (b >> 2)) ^ ((a & 7u) << 3);
                    atomicAdd(&hist[w], 1u << ((b & 3u) << 3));
                }
            }
        }
    }
}

// ---- stats: con/dis/hom + sum(h^2) + cross sum(h_ij*h_ji), swizzle-decoded ----
__device__ __forceinline__ void stats_pass(const uint32_t* hist, int tid, int wave, int lane,
                                           double invnp, double inv2np2,
                                           double& conD, double& disD,
                                           double& homD, double& asmD) {
    uint32_t conU = 0, disU = 0, slinU = 0;
    float homF = 0.0f;
    #pragma unroll 4
    for (int itr = 0; itr < 16; ++itr) {
        int m = tid + (itr << 10);
        uint32_t w = hist[m];
        if (w) {                               // mostly-empty rows skip (execz)
            int i = m >> 6;
            int b4 = (m & 63) ^ ((i & 7) << 3);  // undo swizzle
            int d0 = i - (b4 << 2);
            slinU = udot4acc(w, w, slinU);
            #pragma unroll
            for (int k = 0; k < 4; ++k) {
                uint32_t bv = (w >> (k << 3)) & 0xffu;
                int d = d0 - k;
                uint32_t d2 = (uint32_t)(d * d);
                conU += bv * d2;
                disU += bv * (uint32_t)(d < 0 ? -d : d);
                homF += (float)bv * __builtin_amdgcn_rcpf(1.0f + (float)d2);
            }
        }
    }

    // cross term over 4x4 byte tiles; unit (it=lane, jt=(lane+s)&63)
    uint32_t scrU = 0;
    #pragma unroll
    for (int q = 0; q < 4; ++q) {
        int s = wave + (q << 4);
        int jt = (lane + s) & 63;
        uint32_t A[4], Bw[4];
        #pragma unroll
        for (int k = 0; k < 4; ++k) {
            int ia = 4 * lane + k;
            A[k]  = hist[((ia << 6) | jt)   ^ ((ia & 7) << 3)];
            int ib = 4 * jt + k;
            Bw[k] = hist[((ib << 6) | lane) ^ ((ib & 7) << 3)];
        }
        if ((A[0] | A[1] | A[2] | A[3]) && (Bw[0] | Bw[1] | Bw[2] | Bw[3])) {
            uint32_t x0 = __builtin_amdgcn_perm(Bw[1], Bw[0], 0x05010400u);
            uint32_t x1 = __builtin_amdgcn_perm(Bw[1], Bw[0], 0x07030602u);
            uint32_t x2 = __builtin_amdgcn_perm(Bw[3], Bw[2], 0x05010400u);
            uint32_t x3 = __builtin_amdgcn_perm(Bw[3], Bw[2], 0x07030602u);
            uint32_t t0 = __builtin_amdgcn_perm(x2, x0, 0x05040100u);
            uint32_t t1 = __builtin_amdgcn_perm(x2, x0, 0x07060302u);
            uint32_t t2 = __builtin_amdgcn_perm(x3, x1, 0x05040100u);
            uint32_t t3 = __builtin_amdgcn_perm(x3, x1, 0x07060302u);
            scrU = udot4acc(A[0], t0, scrU);
            scrU = udot4acc(A[1], t1, scrU);
            scrU = udot4acc(A[2], t2, scrU);
            scrU = udot4acc(A[3], t3, scrU);
        }
    }

    conD += (double)conU * invnp;
    disD += (double)disU * invnp;
    homD += (double)homF * invnp;
    asmD += ((double)slinU + (double)scrU) * inv2np2;
}

// ---- fused kernel: one frame per block ----
__global__ __launch_bounds__(NT, 4) void k_fused(const float* __restrict__ x,
                                                 float* __restrict__ out) {
    __shared__ uint32_t gsh[NQ4];      // 49 KB gray frame, 4 px/word
    __shared__ uint32_t hist[16384];   // 64 KB u8 H[256][256], swizzled words
    __shared__ double red[NW * 8];

    const int f = blockIdx.x;
    const int b = f >> 3, fr = f & 7;
    const int tid = threadIdx.x, lane = tid & 63, wave = tid >> 6;

    const float4* xc0 = reinterpret_cast<const float4*>(x + ((size_t)(b * 3 + 0) * 8 + fr) * NPIX);
    const float4* xc1 = reinterpret_cast<const float4*>(x + ((size_t)(b * 3 + 1) * 8 + fr) * NPIX);
    const float4* xc2 = reinterpret_cast<const float4*>(x + ((size_t)(b * 3 + 2) * 8 + fr) * NPIX);

    // phase 0: quantize to LDS gray + std partials (exact int sums)
    uint32_t s1 = 0, s2 = 0;
    for (int i = tid; i < NQ4; i += NT) {
        float4 a = xc0[i], bb = xc1[i], c = xc2[i];
        uint32_t v0 = quant1(a.x + bb.x + c.x);
        uint32_t v1 = quant1(a.y + bb.y + c.y);
        uint32_t v2 = quant1(a.z + bb.z + c.z);
        uint32_t v3 = quant1(a.w + bb.w + c.w);
        gsh[i] = v0 | (v1 << 8) | (v2 << 16) | (v3 << 24);
        s1 += v0 + v1 + v2 + v3;
        s2 += v0 * v0 + v1 * v1 + v2 * v2 + v3 * v3;
    }

    uint4* h4 = reinterpret_cast<uint4*>(hist);
    const uint4 z4 = make_uint4(0u, 0u, 0u, 0u);
    double conD = 0.0, disD = 0.0, homD = 0.0, asmD = 0.0;
    const double invA = 1.0 / 49952.0, invB = 1.0 / 49729.0;           // np even/odd ofs
    const double invA2 = 1.0 / (2.0 * 49952.0 * 49952.0);
    const double invB2 = 1.0 / (2.0 * 49729.0 * 49729.0);

    // ---- offset (0,1) ----
    #pragma unroll
    for (int i = 0; i < 4; ++i) h4[tid + (i << 10)] = z4;
    __syncthreads();
    pair_pass<0, 1>(gsh, hist, wave, lane);
    __syncthreads();
    stats_pass(hist, tid, wave, lane, invA, invA2, conD, disD, homD, asmD);
    __syncthreads();

    // ---- offset (1,1) ----
    #pragma unroll
    for (int i = 0; i < 4; ++i) h4[tid + (i << 10)] = z4;
    __syncthreads();
    pair_pass<1, 1>(gsh, hist, wave, lane);
    __syncthreads();
    stats_pass(hist, tid, wave, lane, invB, invB2, conD, disD, homD, asmD);
    __syncthreads();

    // ---- offset (1,0) ----
    #pragma unroll
    for (int i = 0; i < 4; ++i) h4[tid + (i << 10)] = z4;
    __syncthreads();
    pair_pass<1, 0>(gsh, hist, wave, lane);
    __syncthreads();
    stats_pass(hist, tid, wave, lane, invA, invA2, conD, disD, homD, asmD);
    __syncthreads();

    // ---- offset (1,-1) ----
    #pragma unroll
    for (int i = 0; i < 4; ++i) h4[tid + (i << 10)] = z4;
    __syncthreads();
    pair_pass<1, -1>(gsh, hist, wave, lane);
    __syncthreads();
    stats_pass(hist, tid, wave, lane, invB, invB2, conD, disD, homD, asmD);
    __syncthreads();

    // ---- fused reduction of 6 doubles, finalize in-block ----
    double vals[6] = {(double)s1, (double)s2, conD, disD, homD, asmD};
    #pragma unroll
    for (int off = 32; off; off >>= 1) {
        #pragma unroll
        for (int i = 0; i < 6; ++i) vals[i] += __shfl_down(vals[i], off, 64);
    }
    if (lane == 0) {
        #pragma unroll
        for (int i = 0; i < 6; ++i) red[wave * 8 + i] = vals[i];
    }
    __syncthreads();
    if (tid == 0) {
        double acc[6];
        #pragma unroll
        for (int i = 0; i < 6; ++i) {
            double t = red[i];
            for (int w = 1; w < NW; ++w) t += red[w * 8 + i];
            acc[i] = t;
        }
        double N = (double)NPIX;
        double mean = acc[0] / N;
        double var = acc[1] / N - mean * mean;
        if (var < 0.0) var = 0.0;
        float* op = out + f * 6;
        op[0] = (float)sqrt(var);
        op[1] = (float)(acc[2] * 0.25);
        op[2] = (float)(acc[3] * 0.25);
        op[3] = (float)(acc[4] * 0.25);
        op[4] = (float)(acc[5] * 0.25);
        op[5] = (float)sqrt(acc[5] * 0.25);
    }
}

extern "C" void kernel_launch(void* const* d_in, const int* in_sizes, int n_in,
                              void* d_out, int out_size, void* d_ws, size_t ws_size,
                              hipStream_t stream) {
    const float* x = (const float*)d_in[0];
    float* out = (float*)d_out;
    k_fused<<<NFRAMES, NT, 0, stream>>>(x, out);
}